// Round 10
// baseline (762.184 us; speedup 1.0000x reference)
//
#include <hip/hip_runtime.h>
#include <hip/hip_bf16.h>

// ---------------------------------------------------------------------------
// GIN (3 layers, eps=0) + global mean pool + FC.
//
// Lessons: r1 global f32 atomics = 64B write-through; r2 per-node CSR fill =
//   105MB dirty lines; r3 block-per-bucket agg = latency collapse; r5 linears
//   LDS-read-bound -> r6 MFMA linears; r7 __shfl in divergent flow = garbage
//   (ds_bpermute only serves ACTIVE lanes); r8 1 node/wave = serial-chain
//   bound; r9 4 nodes/wave interleaved BUT inner loop runs to max(deg of 4)
//   with masks -> ~40% padded edge-slots (E[max4 Poisson16]=23 vs 16).
// r10: degree-balanced scheduling. Counting-sort nodes by degree (256 bins,
//   hist folded into bucket_csr) -> perm; waves process perm-order nodes so
//   all 4 nodes per wave have ~equal degree -> masked padding ~0, waves
//   finish together. Per-node arithmetic identical regardless of grouping.
// ---------------------------------------------------------------------------

#define NBLK 256      // blocks for count/fill
#define CFBS 512      // threads for count/fill
#define RB   128      // nodes per bucket
#define NBMAX 1024    // max buckets (N <= 131072)
#define SCBS 1024     // scan chunk

__device__ inline float bf2f(unsigned short u) {
    return __uint_as_float((unsigned)u << 16);
}
__device__ inline unsigned short f2bf(float f) {
    unsigned x = __float_as_uint(f);
    return (unsigned short)((x + 0x7FFFu + ((x >> 16) & 1u)) >> 16);  // RNE
}
__device__ inline float lo16(unsigned u) { return __uint_as_float(u << 16); }
__device__ inline float hi16(unsigned u) { return __uint_as_float(u & 0xFFFF0000u); }

// ---- bucket build ---------------------------------------------------------

__global__ __launch_bounds__(CFBS) void count_kernel(
    const int* __restrict__ dst, int* __restrict__ cnt, int E, int NB)
{
    __shared__ int hist[NBMAX];
    int tid = threadIdx.x;
    for (int i = tid; i < NBMAX; i += CFBS) hist[i] = 0;
    __syncthreads();
    for (int e = blockIdx.x * CFBS + tid; e < E; e += NBLK * CFBS)
        atomicAdd(&hist[dst[e] >> 7], 1);
    __syncthreads();
    for (int b = tid; b < NB; b += CFBS)
        cnt[b * NBLK + blockIdx.x] = hist[b];
}

__global__ __launch_bounds__(SCBS) void scan_k1(
    const int* __restrict__ cnt, int* __restrict__ ofs,
    int* __restrict__ part, int NT)
{
    __shared__ int tmp[SCBS];
    int i = blockIdx.x * SCBS + threadIdx.x;
    int v = (i < NT) ? cnt[i] : 0;
    tmp[threadIdx.x] = v;
    __syncthreads();
    for (int off = 1; off < SCBS; off <<= 1) {
        int t = (threadIdx.x >= off) ? tmp[threadIdx.x - off] : 0;
        __syncthreads();
        tmp[threadIdx.x] += t;
        __syncthreads();
    }
    if (i < NT) ofs[i] = tmp[threadIdx.x] - v;   // exclusive within chunk
    if (threadIdx.x == SCBS - 1) part[blockIdx.x] = tmp[threadIdx.x];
}

__global__ __launch_bounds__(SCBS) void scan_k2(int* __restrict__ part, int B)
{
    __shared__ int tmp[SCBS];
    int v = (threadIdx.x < B) ? part[threadIdx.x] : 0;
    tmp[threadIdx.x] = v;
    __syncthreads();
    for (int off = 1; off < SCBS; off <<= 1) {
        int t = (threadIdx.x >= off) ? tmp[threadIdx.x - off] : 0;
        __syncthreads();
        tmp[threadIdx.x] += t;
        __syncthreads();
    }
    if (threadIdx.x < B) part[threadIdx.x] = tmp[threadIdx.x] - v;
}

__global__ __launch_bounds__(SCBS) void scan_k3(
    int* __restrict__ ofs, const int* __restrict__ part, int NT)
{
    int i = blockIdx.x * SCBS + threadIdx.x;
    if (i < NT) ofs[i] += part[blockIdx.x];
}

__global__ __launch_bounds__(CFBS) void fillp_kernel(
    const int* __restrict__ src, const int* __restrict__ dst,
    const int* __restrict__ ofs, int* __restrict__ pairs, int E, int NB)
{
    __shared__ int cur[NBMAX];
    int tid = threadIdx.x;
    for (int b = tid; b < NB; b += CFBS)
        cur[b] = ofs[b * NBLK + blockIdx.x];
    __syncthreads();
    for (int e = blockIdx.x * CFBS + tid; e < E; e += NBLK * CFBS) {
        int d = dst[e];
        int b = d >> 7, dl = d & 127;
        int pos = atomicAdd(&cur[b], 1);
        pairs[pos] = (dl << 20) | src[e];
    }
}

// per-bucket CSR finalize + global degree histogram (256 bins)
__global__ __launch_bounds__(512) void bucket_csr_kernel(
    const int* __restrict__ pairs, const int* __restrict__ ofs,
    int* __restrict__ rowstart, int* __restrict__ eidx,
    int* __restrict__ dcnt, int N, int E, int NB)
{
    __shared__ int deg[RB], pfx[RB], cur[RB];
    int tid = threadIdx.x;
    int b = blockIdx.x, n0 = b << 7;
    int e0 = ofs[b * NBLK];
    int e1 = (b + 1 < NB) ? ofs[(b + 1) * NBLK] : E;
    if (tid < RB) deg[tid] = 0;
    __syncthreads();
    for (int e = e0 + tid; e < e1; e += 512)
        atomicAdd(&deg[pairs[e] >> 20], 1);
    __syncthreads();
    if (tid < RB) pfx[tid] = deg[tid];
    __syncthreads();
    for (int off = 1; off < RB; off <<= 1) {
        int t = (tid < RB && tid >= off) ? pfx[tid - off] : 0;
        __syncthreads();
        if (tid < RB) pfx[tid] += t;
        __syncthreads();
    }
    if (tid < RB) {
        int ex = pfx[tid] - deg[tid];     // exclusive
        cur[tid] = ex;
        int n = n0 + tid;
        if (n < N) {
            rowstart[n] = e0 + ex;
            atomicAdd(&dcnt[min(deg[tid], 255)], 1);   // degree histogram
        }
    }
    if (b == NB - 1 && tid == 0) rowstart[N] = E;
    __syncthreads();
    for (int e = e0 + tid; e < e1; e += 512) {
        int p = pairs[e];
        int pos = e0 + atomicAdd(&cur[p >> 20], 1);
        eidx[pos] = p & 0xFFFFF;
    }
}

// exclusive scan of the 256 degree bins (single block)
__global__ __launch_bounds__(256) void dscan_kernel(int* __restrict__ dcnt)
{
    __shared__ int tmp[256];
    int i = threadIdx.x;
    int v = dcnt[i];
    tmp[i] = v;
    __syncthreads();
    for (int off = 1; off < 256; off <<= 1) {
        int t = (i >= off) ? tmp[i - off] : 0;
        __syncthreads();
        tmp[i] += t;
        __syncthreads();
    }
    dcnt[i] = tmp[i] - v;   // exclusive; becomes the fill cursor
}

// scatter node ids into perm, ordered by degree bin (order within bin = any;
// per-node arithmetic is independent of grouping, outputs bit-identical)
__global__ __launch_bounds__(256) void dfill_kernel(
    const int* __restrict__ rs, int* __restrict__ dcur,
    int* __restrict__ perm, int N)
{
    int n = blockIdx.x * 256 + threadIdx.x;
    if (n >= N) return;
    int d = min(rs[n + 1] - rs[n], 255);
    int pos = atomicAdd(&dcur[d], 1);
    perm[pos] = n;
}

// ---- x prep: xb[N][16] bf16 (pad 9->16) ----------------------------------

__global__ __launch_bounds__(256) void xprep_kernel(
    const float* __restrict__ x, unsigned short* __restrict__ xb, int N)
{
    int n = blockIdx.x * 256 + threadIdx.x;
    if (n >= N) return;
    unsigned short r[16];
    #pragma unroll
    for (int k = 0; k < 9; ++k) r[k] = f2bf(x[(size_t)n * 9 + k]);
    #pragma unroll
    for (int k = 9; k < 16; ++k) r[k] = 0;
    uint4 u0, u1;
    u0.x = r[0] | ((unsigned)r[1] << 16);  u0.y = r[2] | ((unsigned)r[3] << 16);
    u0.z = r[4] | ((unsigned)r[5] << 16);  u0.w = r[6] | ((unsigned)r[7] << 16);
    u1.x = r[8] | ((unsigned)r[9] << 16);  u1.y = 0; u1.z = 0; u1.w = 0;
    *(uint4*)&xb[(size_t)n * 16]     = u0;
    *(uint4*)&xb[(size_t)n * 16 + 8] = u1;
}

// ---- layer 1: 9-dim gather + Lin 9->64 + relu, 4 perm-nodes per wave -----

__global__ __launch_bounds__(256) void node1v_kernel(
    const unsigned short* __restrict__ xb, const int* __restrict__ rs,
    const int* __restrict__ eidx, const int* __restrict__ perm,
    const float* __restrict__ W1, const float* __restrict__ b1,
    unsigned short* __restrict__ h1, int N)
{
    __shared__ float Wl[576];
    __shared__ float bl[64];
    for (int i = threadIdx.x; i < 576; i += 256) Wl[i] = W1[i];
    if (threadIdx.x < 64) bl[threadIdx.x] = b1[threadIdx.x];
    __syncthreads();
    int wid = threadIdx.x >> 6;
    int lane = threadIdx.x & 63;
    int g  = lane >> 2;     // edge group 0..15
    int d4 = lane & 3;      // dims 4*d4 .. 4*d4+3
    int nb = blockIdx.x * 16 + wid * 4;   // this wave's 4 perm slots
    if (nb >= N) return;

    int n[4], e0[4], dg[4];
    float A0[4], A1[4], A2[4], A3[4];
    #pragma unroll
    for (int i = 0; i < 4; ++i) {
        n[i] = perm[min(nb + i, N - 1)];
        e0[i] = rs[n[i]];
        dg[i] = rs[n[i] + 1] - e0[i];
        A0[i] = A1[i] = A2[i] = A3[i] = 0.f;
    }
    #pragma unroll
    for (int i = 0; i < 4; ++i) {
        if (g == 0) {       // self term
            uint2 u = *(const uint2*)&xb[(size_t)n[i] * 16 + d4 * 4];
            A0[i] += lo16(u.x); A1[i] += hi16(u.x);
            A2[i] += lo16(u.y); A3[i] += hi16(u.y);
        }
    }
    int mdeg = max(max(dg[0], dg[1]), max(dg[2], dg[3]));
    for (int w0 = 0; w0 < mdeg; w0 += 64) {
        int sidx[4], wd[4];
        #pragma unroll
        for (int i = 0; i < 4; ++i) {
            wd[i] = min(max(dg[i] - w0, 0), 64);
            sidx[i] = (lane < wd[i]) ? eidx[e0[i] + w0 + lane] : 0;
        }
        int mwd = max(max(wd[0], wd[1]), max(wd[2], wd[3]));
        for (int c = 0; c < mwd; c += 16) {
            #pragma unroll
            for (int i = 0; i < 4; ++i) {
                int idx = c + g;
                int s = __shfl(sidx[i], idx < wd[i] ? idx : 0); // uniform flow
                float m = (idx < wd[i]) ? 1.f : 0.f;
                uint2 u = *(const uint2*)&xb[(size_t)s * 16 + d4 * 4];
                A0[i] += m * lo16(u.x); A1[i] += m * hi16(u.x);
                A2[i] += m * lo16(u.y); A3[i] += m * hi16(u.y);
            }
        }
    }
    #pragma unroll
    for (int m = 4; m < 64; m <<= 1) {
        #pragma unroll
        for (int i = 0; i < 4; ++i) {
            A0[i] += __shfl_xor(A0[i], m); A1[i] += __shfl_xor(A1[i], m);
            A2[i] += __shfl_xor(A2[i], m); A3[i] += __shfl_xor(A3[i], m);
        }
    }
    const float* wr = &Wl[lane * 9];
    #pragma unroll
    for (int i = 0; i < 4; ++i) {
        float xv0 = __shfl(A0[i], 0), xv1 = __shfl(A1[i], 0);
        float xv2 = __shfl(A2[i], 0), xv3 = __shfl(A3[i], 0);
        float xv4 = __shfl(A0[i], 1), xv5 = __shfl(A1[i], 1);
        float xv6 = __shfl(A2[i], 1), xv7 = __shfl(A3[i], 1);
        float xv8 = __shfl(A0[i], 2);
        float s = bl[lane] + xv0 * wr[0] + xv1 * wr[1] + xv2 * wr[2]
                + xv3 * wr[3] + xv4 * wr[4] + xv5 * wr[5] + xv6 * wr[6]
                + xv7 * wr[7] + xv8 * wr[8];
        if (nb + i < N)
            h1[(size_t)n[i] * 64 + lane] = f2bf(fmaxf(s, 0.f));
    }
}

// ---- 64-dim gather, 4 perm-nodes per wave: 4 edge-grp x 16 dim-grp -------

template<bool BIAS_RELU>
__global__ __launch_bounds__(256) void gather64v_kernel(
    const unsigned short* __restrict__ feat, const int* __restrict__ rs,
    const int* __restrict__ eidx, const int* __restrict__ perm,
    const float* __restrict__ bias, unsigned short* __restrict__ out, int N)
{
    int wid = threadIdx.x >> 6;
    int lane = threadIdx.x & 63;
    int g  = lane >> 4;     // edge group 0..3
    int d4 = lane & 15;     // dims 4*d4 .. 4*d4+3
    int nb = blockIdx.x * 16 + wid * 4;
    if (nb >= N) return;

    int n[4], e0[4], dg[4];
    float A0[4], A1[4], A2[4], A3[4];
    #pragma unroll
    for (int i = 0; i < 4; ++i) {
        n[i] = perm[min(nb + i, N - 1)];
        e0[i] = rs[n[i]];
        dg[i] = rs[n[i] + 1] - e0[i];
        A0[i] = A1[i] = A2[i] = A3[i] = 0.f;
    }
    #pragma unroll
    for (int i = 0; i < 4; ++i) {
        if (g == 0) {       // self term
            uint2 u = *(const uint2*)&feat[(size_t)n[i] * 64 + d4 * 4];
            A0[i] += lo16(u.x); A1[i] += hi16(u.x);
            A2[i] += lo16(u.y); A3[i] += hi16(u.y);
        }
    }
    int mdeg = max(max(dg[0], dg[1]), max(dg[2], dg[3]));
    for (int w0 = 0; w0 < mdeg; w0 += 64) {
        int sidx[4], wd[4];
        #pragma unroll
        for (int i = 0; i < 4; ++i) {
            wd[i] = min(max(dg[i] - w0, 0), 64);
            sidx[i] = (lane < wd[i]) ? eidx[e0[i] + w0 + lane] : 0;
        }
        int mwd = max(max(wd[0], wd[1]), max(wd[2], wd[3]));
        for (int c = 0; c < mwd; c += 8) {
            #pragma unroll
            for (int i = 0; i < 4; ++i) {
                int i0 = c + g, i1 = c + 4 + g;
                int s0 = __shfl(sidx[i], i0 < wd[i] ? i0 : 0);  // uniform flow
                int s1 = __shfl(sidx[i], i1 < wd[i] ? i1 : 0);
                float m0 = (i0 < wd[i]) ? 1.f : 0.f;
                float m1 = (i1 < wd[i]) ? 1.f : 0.f;
                uint2 u0 = *(const uint2*)&feat[(size_t)s0 * 64 + d4 * 4];
                uint2 u1 = *(const uint2*)&feat[(size_t)s1 * 64 + d4 * 4];
                A0[i] += m0 * lo16(u0.x) + m1 * lo16(u1.x);
                A1[i] += m0 * hi16(u0.x) + m1 * hi16(u1.x);
                A2[i] += m0 * lo16(u0.y) + m1 * lo16(u1.y);
                A3[i] += m0 * hi16(u0.y) + m1 * hi16(u1.y);
            }
        }
    }
    #pragma unroll
    for (int m = 16; m < 64; m <<= 1) {
        #pragma unroll
        for (int i = 0; i < 4; ++i) {
            A0[i] += __shfl_xor(A0[i], m); A1[i] += __shfl_xor(A1[i], m);
            A2[i] += __shfl_xor(A2[i], m); A3[i] += __shfl_xor(A3[i], m);
        }
    }
    float4 bv = make_float4(0.f, 0.f, 0.f, 0.f);
    if (BIAS_RELU) bv = *(const float4*)&bias[d4 * 4];
    #pragma unroll
    for (int i = 0; i < 4; ++i) {
        if (g == 0 && nb + i < N) {
            float a0 = A0[i], a1 = A1[i], a2 = A2[i], a3 = A3[i];
            if (BIAS_RELU) {
                a0 = fmaxf(a0 + bv.x, 0.f); a1 = fmaxf(a1 + bv.y, 0.f);
                a2 = fmaxf(a2 + bv.z, 0.f); a3 = fmaxf(a3 + bv.w, 0.f);
            }
            ushort4 u;
            u.x = f2bf(a0); u.y = f2bf(a1); u.z = f2bf(a2); u.w = f2bf(a3);
            *(ushort4*)&out[(size_t)n[i] * 64 + d4 * 4] = u;
        }
    }
}

// ---- MFMA linear: Y[n,:OUT] = relu?(A[n,:IN] @ W^T + bias), bf16 tables ---

template<int IN, int OUT, bool RELU>
__global__ __launch_bounds__(256) void linear_mfma_kernel(
    const unsigned short* __restrict__ A, const float* __restrict__ W,
    const float* __restrict__ bias, unsigned short* __restrict__ Y, int N)
{
    using s8v = __attribute__((ext_vector_type(8))) short;
    using f4v = __attribute__((ext_vector_type(4))) float;
    constexpr int KT = IN / 32;       // K-steps
    constexpr int CT = OUT / 16;      // col tiles
    constexpr int INP = IN + 8;       // padded row stride (ushorts)
    __shared__ __align__(16) unsigned short Wb[OUT * INP];
    __shared__ float bl[OUT];
    int tid = threadIdx.x;
    for (int i = tid; i < OUT * IN; i += 256) {
        int o = i / IN, k = i % IN;
        Wb[o * INP + k] = f2bf(W[i]);
    }
    for (int i = tid; i < OUT; i += 256) bl[i] = bias ? bias[i] : 0.f;
    __syncthreads();

    int w = tid >> 6, lane = tid & 63;
    int n0 = blockIdx.x * 64 + w * 16;
    int hl = lane >> 4;               // k-slice 0..3
    int ll = lane & 15;               // row (A) / col (B)

    int an = n0 + ll;
    if (an >= N) an = N - 1;          // clamp: garbage rows never written
    const unsigned short* arow = &A[(size_t)an * IN + hl * 8];
    s8v a[KT];
    #pragma unroll
    for (int ks = 0; ks < KT; ++ks) a[ks] = *(const s8v*)&arow[ks * 32];

    f4v acc[CT];
    #pragma unroll
    for (int c = 0; c < CT; ++c) acc[c] = (f4v){0.f, 0.f, 0.f, 0.f};
    #pragma unroll
    for (int c = 0; c < CT; ++c) {
        const unsigned short* wrow = &Wb[(c * 16 + ll) * INP + hl * 8];
        #pragma unroll
        for (int ks = 0; ks < KT; ++ks) {
            s8v b = *(const s8v*)&wrow[ks * 32];
            acc[c] = __builtin_amdgcn_mfma_f32_16x16x32_bf16(a[ks], b, acc[c], 0, 0, 0);
        }
    }
    #pragma unroll
    for (int c = 0; c < CT; ++c) {
        int col = c * 16 + ll;
        float bv = bl[col];
        #pragma unroll
        for (int r = 0; r < 4; ++r) {
            int gn = n0 + hl * 4 + r;
            if (gn < N) {
                float v = acc[c][r] + bv;
                if (RELU) v = fmaxf(v, 0.f);
                Y[(size_t)gn * OUT + col] = f2bf(v);
            }
        }
    }
}

// ---- pool + FC ------------------------------------------------------------

__device__ inline int lower_bound_i(const int* a, int n, int v) {
    int lo = 0, hi = n;
    while (lo < hi) {
        int mid = (lo + hi) >> 1;
        if (a[mid] < v) lo = mid + 1; else hi = mid;
    }
    return lo;
}

__global__ __launch_bounds__(256) void pool_fc_kernel(
    const unsigned short* __restrict__ h3, const int* __restrict__ batch,
    const float* __restrict__ Wfc, const float* __restrict__ bfc,
    float* __restrict__ out, int N)
{
    int g = blockIdx.x;
    int tid = threadIdx.x;
    int w = tid >> 6, lane = tid & 63;
    int lo = lower_bound_i(batch, N, g);
    int hi = lower_bound_i(batch, N, g + 1);
    float sum = 0.f;
    for (int i = lo + w; i < hi; i += 4)
        sum += bf2f(h3[(size_t)i * 64 + lane]);
    __shared__ float P[4][64];
    P[w][lane] = sum;
    __syncthreads();
    if (w == 0) {
        float s = P[0][lane] + P[1][lane] + P[2][lane] + P[3][lane];
        float cnt = (float)((hi - lo) > 0 ? (hi - lo) : 1);
        P[0][lane] = s / cnt;
    }
    __syncthreads();
    if (tid < 11) {
        float s = bfc[tid];
        const float* wr = &Wfc[tid * 64];
        #pragma unroll 8
        for (int k = 0; k < 64; ++k) s += P[0][k] * wr[k];
        out[g * 11 + tid] = s;
    }
}

// ---------------------------------------------------------------------------

extern "C" void kernel_launch(void* const* d_in, const int* in_sizes, int n_in,
                              void* d_out, int out_size, void* d_ws, size_t ws_size,
                              hipStream_t stream) {
    const float* x    = (const float*)d_in[0];
    const int*   ei   = (const int*)d_in[1];
    const int*   batch= (const int*)d_in[2];
    const float* W1   = (const float*)d_in[3];
    const float* b1   = (const float*)d_in[4];
    const float* W2   = (const float*)d_in[5];
    const float* b2   = (const float*)d_in[6];
    const float* W3   = (const float*)d_in[7];
    const float* b3   = (const float*)d_in[8];
    const float* Wfc  = (const float*)d_in[9];
    const float* bfc  = (const float*)d_in[10];
    float* out = (float*)d_out;

    const int N = in_sizes[2];
    const int E = in_sizes[1] / 2;
    const int G = out_size / 11;
    const int* src = ei;
    const int* dst = ei + E;
    const int NB = (N + RB - 1) / RB;      // buckets
    const int NT = NB * NBLK;              // count entries
    const int SB = (NT + SCBS - 1) / SCBS; // scan chunks

    // workspace (all bf16 tables):
    //   B1 64N (h1 -> t3) | B2 64N (buf2 -> h3) | B3 128N (h2) | XB 16N (xb)
    //   ints: pairs E | eidx E | rowstart N+1 | perm N | dcnt 256 |
    //         cnt NT | ofs NT | part SCBS
    unsigned short* B1 = (unsigned short*)d_ws;
    unsigned short* B2 = B1 + (size_t)64 * N;
    unsigned short* B3 = B2 + (size_t)64 * N;
    unsigned short* XB = B3 + (size_t)128 * N;
    int* pairs    = (int*)(XB + (size_t)16 * N);
    int* eidx     = pairs + E;
    int* rowstart = eidx + E;
    int* perm     = rowstart + (N + 1);
    int* dcnt     = perm + N;
    int* cnt      = dcnt + 256;
    int* ofs      = cnt + NT;
    int* part     = ofs + NT;

    unsigned short* h1   = B1;
    unsigned short* buf2 = B2;
    unsigned short* h2   = B3;
    unsigned short* t3   = B1;   // h1 dead after gather2
    unsigned short* h3   = B2;   // buf2 dead after lin2
    unsigned short* xb   = XB;

    // ---- build: bucket-grouped pairs, per-bucket CSR, degree-sort perm ----
    count_kernel<<<NBLK, CFBS, 0, stream>>>(dst, cnt, E, NB);
    scan_k1<<<SB, SCBS, 0, stream>>>(cnt, ofs, part, NT);
    scan_k2<<<1, SCBS, 0, stream>>>(part, SB);
    scan_k3<<<SB, SCBS, 0, stream>>>(ofs, part, NT);
    fillp_kernel<<<NBLK, CFBS, 0, stream>>>(src, dst, ofs, pairs, E, NB);
    hipMemsetAsync(dcnt, 0, 256 * sizeof(int), stream);
    bucket_csr_kernel<<<NB, 512, 0, stream>>>(pairs, ofs, rowstart, eidx, dcnt, N, E, NB);
    dscan_kernel<<<1, 256, 0, stream>>>(dcnt);
    dfill_kernel<<<(N + 255) / 256, 256, 0, stream>>>(rowstart, dcnt, perm, N);
    xprep_kernel<<<(N + 255) / 256, 256, 0, stream>>>(x, xb, N);

    // ---- layer 1: vectorized 9-dim gather + Lin 9->64 + relu ----
    node1v_kernel<<<(N + 15) / 16, 256, 0, stream>>>(
        xb, rowstart, eidx, perm, W1, b1, h1, N);

    // ---- layer 2 ----
    gather64v_kernel<false><<<(N + 15) / 16, 256, 0, stream>>>(
        h1, rowstart, eidx, perm, nullptr, buf2, N);
    linear_mfma_kernel<64, 128, true><<<(N + 63) / 64, 256, 0, stream>>>(
        buf2, W2, b2, h2, N);

    // ---- layer 3 ----
    linear_mfma_kernel<128, 64, false><<<(N + 63) / 64, 256, 0, stream>>>(
        h2, W3, nullptr, t3, N);
    gather64v_kernel<true><<<(N + 15) / 16, 256, 0, stream>>>(
        t3, rowstart, eidx, perm, b3, h3, N);

    // ---- pool + FC ----
    pool_fc_kernel<<<G, 256, 0, stream>>>(h3, batch, Wfc, bfc, out, N);
}

// Round 11
// 224.497 us; speedup vs baseline: 3.3951x; 3.3951x over previous
//
#include <hip/hip_runtime.h>
#include <hip/hip_bf16.h>

// ---------------------------------------------------------------------------
// GIN (3 layers, eps=0) + global mean pool + FC.
//
// Lessons: r1 global f32 atomics = 64B write-through; r2 per-node CSR fill =
//   105MB dirty lines; r3 block-per-bucket agg = latency collapse; r5 linears
//   LDS-read-bound -> r6 MFMA linears; r7 __shfl in divergent flow = garbage;
//   r8 1 node/wave = serial-chain bound; r9 4 nodes/wave interleaved (+ILP);
//   r10 degree-sort idea OK but built with PER-NODE GLOBAL atomics on 256
//   hot bins (Poisson(16): ~10k nodes/bin) -> same-address RMW serialization
//   ~280us x2 kernels.
// r11: degree-sort rebuilt contention-free with the proven two-phase LDS-
//   cursor pattern: per-block LDS hist -> (bin,block) counts -> scan ->
//   LDS-cursor scatter. Global traffic = plain writes only.
// ---------------------------------------------------------------------------

#define NBLK 256      // blocks for edge count/fill
#define CFBS 512      // threads for edge count/fill
#define RB   128      // nodes per bucket
#define NBMAX 1024    // max buckets (N <= 131072)
#define SCBS 1024     // scan chunk
#define DBLK 64       // blocks for degree count/fill

__device__ inline float bf2f(unsigned short u) {
    return __uint_as_float((unsigned)u << 16);
}
__device__ inline unsigned short f2bf(float f) {
    unsigned x = __float_as_uint(f);
    return (unsigned short)((x + 0x7FFFu + ((x >> 16) & 1u)) >> 16);  // RNE
}
__device__ inline float lo16(unsigned u) { return __uint_as_float(u << 16); }
__device__ inline float hi16(unsigned u) { return __uint_as_float(u & 0xFFFF0000u); }

// ---- bucket build ---------------------------------------------------------

__global__ __launch_bounds__(CFBS) void count_kernel(
    const int* __restrict__ dst, int* __restrict__ cnt, int E, int NB)
{
    __shared__ int hist[NBMAX];
    int tid = threadIdx.x;
    for (int i = tid; i < NBMAX; i += CFBS) hist[i] = 0;
    __syncthreads();
    for (int e = blockIdx.x * CFBS + tid; e < E; e += NBLK * CFBS)
        atomicAdd(&hist[dst[e] >> 7], 1);
    __syncthreads();
    for (int b = tid; b < NB; b += CFBS)
        cnt[b * NBLK + blockIdx.x] = hist[b];
}

__global__ __launch_bounds__(SCBS) void scan_k1(
    const int* __restrict__ cnt, int* __restrict__ ofs,
    int* __restrict__ part, int NT)
{
    __shared__ int tmp[SCBS];
    int i = blockIdx.x * SCBS + threadIdx.x;
    int v = (i < NT) ? cnt[i] : 0;
    tmp[threadIdx.x] = v;
    __syncthreads();
    for (int off = 1; off < SCBS; off <<= 1) {
        int t = (threadIdx.x >= off) ? tmp[threadIdx.x - off] : 0;
        __syncthreads();
        tmp[threadIdx.x] += t;
        __syncthreads();
    }
    if (i < NT) ofs[i] = tmp[threadIdx.x] - v;   // exclusive within chunk
    if (threadIdx.x == SCBS - 1) part[blockIdx.x] = tmp[threadIdx.x];
}

__global__ __launch_bounds__(SCBS) void scan_k2(int* __restrict__ part, int B)
{
    __shared__ int tmp[SCBS];
    int v = (threadIdx.x < B) ? part[threadIdx.x] : 0;
    tmp[threadIdx.x] = v;
    __syncthreads();
    for (int off = 1; off < SCBS; off <<= 1) {
        int t = (threadIdx.x >= off) ? tmp[threadIdx.x - off] : 0;
        __syncthreads();
        tmp[threadIdx.x] += t;
        __syncthreads();
    }
    if (threadIdx.x < B) part[threadIdx.x] = tmp[threadIdx.x] - v;
}

__global__ __launch_bounds__(SCBS) void scan_k3(
    int* __restrict__ ofs, const int* __restrict__ part, int NT)
{
    int i = blockIdx.x * SCBS + threadIdx.x;
    if (i < NT) ofs[i] += part[blockIdx.x];
}

__global__ __launch_bounds__(CFBS) void fillp_kernel(
    const int* __restrict__ src, const int* __restrict__ dst,
    const int* __restrict__ ofs, int* __restrict__ pairs, int E, int NB)
{
    __shared__ int cur[NBMAX];
    int tid = threadIdx.x;
    for (int b = tid; b < NB; b += CFBS)
        cur[b] = ofs[b * NBLK + blockIdx.x];
    __syncthreads();
    for (int e = blockIdx.x * CFBS + tid; e < E; e += NBLK * CFBS) {
        int d = dst[e];
        int b = d >> 7, dl = d & 127;
        int pos = atomicAdd(&cur[b], 1);
        pairs[pos] = (dl << 20) | src[e];
    }
}

// per-bucket CSR finalize (r9 form: no global histogram)
__global__ __launch_bounds__(512) void bucket_csr_kernel(
    const int* __restrict__ pairs, const int* __restrict__ ofs,
    int* __restrict__ rowstart, int* __restrict__ eidx, int N, int E, int NB)
{
    __shared__ int deg[RB], pfx[RB], cur[RB];
    int tid = threadIdx.x;
    int b = blockIdx.x, n0 = b << 7;
    int e0 = ofs[b * NBLK];
    int e1 = (b + 1 < NB) ? ofs[(b + 1) * NBLK] : E;
    if (tid < RB) deg[tid] = 0;
    __syncthreads();
    for (int e = e0 + tid; e < e1; e += 512)
        atomicAdd(&deg[pairs[e] >> 20], 1);
    __syncthreads();
    if (tid < RB) pfx[tid] = deg[tid];
    __syncthreads();
    for (int off = 1; off < RB; off <<= 1) {
        int t = (tid < RB && tid >= off) ? pfx[tid - off] : 0;
        __syncthreads();
        if (tid < RB) pfx[tid] += t;
        __syncthreads();
    }
    if (tid < RB) {
        int ex = pfx[tid] - deg[tid];     // exclusive
        cur[tid] = ex;
        int n = n0 + tid;
        if (n < N) rowstart[n] = e0 + ex;
    }
    if (b == NB - 1 && tid == 0) rowstart[N] = E;
    __syncthreads();
    for (int e = e0 + tid; e < e1; e += 512) {
        int p = pairs[e];
        int pos = e0 + atomicAdd(&cur[p >> 20], 1);
        eidx[pos] = p & 0xFFFFF;
    }
}

// ---- degree-sort (contention-free two-phase, LDS cursors) ----------------

// per-block LDS degree histogram -> (bin, block) counts
__global__ __launch_bounds__(256) void dcount_kernel(
    const int* __restrict__ rs, int* __restrict__ dcnt, int N)
{
    __shared__ int hist[256];
    int tid = threadIdx.x;
    hist[tid] = 0;
    __syncthreads();
    for (int n = blockIdx.x * 256 + tid; n < N; n += DBLK * 256)
        atomicAdd(&hist[min(rs[n + 1] - rs[n], 255)], 1);
    __syncthreads();
    dcnt[tid * DBLK + blockIdx.x] = hist[tid];
}

// scatter node ids into perm (LDS cursors seeded from scanned offsets).
// Per-node arithmetic is independent of grouping -> outputs bit-identical.
__global__ __launch_bounds__(256) void dfillk_kernel(
    const int* __restrict__ rs, const int* __restrict__ dofs,
    int* __restrict__ perm, int N)
{
    __shared__ int cur[256];
    int tid = threadIdx.x;
    cur[tid] = dofs[tid * DBLK + blockIdx.x];
    __syncthreads();
    for (int n = blockIdx.x * 256 + tid; n < N; n += DBLK * 256) {
        int d = min(rs[n + 1] - rs[n], 255);
        int pos = atomicAdd(&cur[d], 1);
        perm[pos] = n;
    }
}

// ---- x prep: xb[N][16] bf16 (pad 9->16) ----------------------------------

__global__ __launch_bounds__(256) void xprep_kernel(
    const float* __restrict__ x, unsigned short* __restrict__ xb, int N)
{
    int n = blockIdx.x * 256 + threadIdx.x;
    if (n >= N) return;
    unsigned short r[16];
    #pragma unroll
    for (int k = 0; k < 9; ++k) r[k] = f2bf(x[(size_t)n * 9 + k]);
    #pragma unroll
    for (int k = 9; k < 16; ++k) r[k] = 0;
    uint4 u0, u1;
    u0.x = r[0] | ((unsigned)r[1] << 16);  u0.y = r[2] | ((unsigned)r[3] << 16);
    u0.z = r[4] | ((unsigned)r[5] << 16);  u0.w = r[6] | ((unsigned)r[7] << 16);
    u1.x = r[8] | ((unsigned)r[9] << 16);  u1.y = 0; u1.z = 0; u1.w = 0;
    *(uint4*)&xb[(size_t)n * 16]     = u0;
    *(uint4*)&xb[(size_t)n * 16 + 8] = u1;
}

// ---- layer 1: 9-dim gather + Lin 9->64 + relu, 4 perm-nodes per wave -----

__global__ __launch_bounds__(256) void node1v_kernel(
    const unsigned short* __restrict__ xb, const int* __restrict__ rs,
    const int* __restrict__ eidx, const int* __restrict__ perm,
    const float* __restrict__ W1, const float* __restrict__ b1,
    unsigned short* __restrict__ h1, int N)
{
    __shared__ float Wl[576];
    __shared__ float bl[64];
    for (int i = threadIdx.x; i < 576; i += 256) Wl[i] = W1[i];
    if (threadIdx.x < 64) bl[threadIdx.x] = b1[threadIdx.x];
    __syncthreads();
    int wid = threadIdx.x >> 6;
    int lane = threadIdx.x & 63;
    int g  = lane >> 2;     // edge group 0..15
    int d4 = lane & 3;      // dims 4*d4 .. 4*d4+3
    int nb = blockIdx.x * 16 + wid * 4;   // this wave's 4 perm slots
    if (nb >= N) return;

    int n[4], e0[4], dg[4];
    float A0[4], A1[4], A2[4], A3[4];
    #pragma unroll
    for (int i = 0; i < 4; ++i) {
        n[i] = perm[min(nb + i, N - 1)];
        e0[i] = rs[n[i]];
        dg[i] = rs[n[i] + 1] - e0[i];
        A0[i] = A1[i] = A2[i] = A3[i] = 0.f;
    }
    #pragma unroll
    for (int i = 0; i < 4; ++i) {
        if (g == 0) {       // self term
            uint2 u = *(const uint2*)&xb[(size_t)n[i] * 16 + d4 * 4];
            A0[i] += lo16(u.x); A1[i] += hi16(u.x);
            A2[i] += lo16(u.y); A3[i] += hi16(u.y);
        }
    }
    int mdeg = max(max(dg[0], dg[1]), max(dg[2], dg[3]));
    for (int w0 = 0; w0 < mdeg; w0 += 64) {
        int sidx[4], wd[4];
        #pragma unroll
        for (int i = 0; i < 4; ++i) {
            wd[i] = min(max(dg[i] - w0, 0), 64);
            sidx[i] = (lane < wd[i]) ? eidx[e0[i] + w0 + lane] : 0;
        }
        int mwd = max(max(wd[0], wd[1]), max(wd[2], wd[3]));
        for (int c = 0; c < mwd; c += 16) {
            #pragma unroll
            for (int i = 0; i < 4; ++i) {
                int idx = c + g;
                int s = __shfl(sidx[i], idx < wd[i] ? idx : 0); // uniform flow
                float m = (idx < wd[i]) ? 1.f : 0.f;
                uint2 u = *(const uint2*)&xb[(size_t)s * 16 + d4 * 4];
                A0[i] += m * lo16(u.x); A1[i] += m * hi16(u.x);
                A2[i] += m * lo16(u.y); A3[i] += m * hi16(u.y);
            }
        }
    }
    #pragma unroll
    for (int m = 4; m < 64; m <<= 1) {
        #pragma unroll
        for (int i = 0; i < 4; ++i) {
            A0[i] += __shfl_xor(A0[i], m); A1[i] += __shfl_xor(A1[i], m);
            A2[i] += __shfl_xor(A2[i], m); A3[i] += __shfl_xor(A3[i], m);
        }
    }
    const float* wr = &Wl[lane * 9];
    #pragma unroll
    for (int i = 0; i < 4; ++i) {
        float xv0 = __shfl(A0[i], 0), xv1 = __shfl(A1[i], 0);
        float xv2 = __shfl(A2[i], 0), xv3 = __shfl(A3[i], 0);
        float xv4 = __shfl(A0[i], 1), xv5 = __shfl(A1[i], 1);
        float xv6 = __shfl(A2[i], 1), xv7 = __shfl(A3[i], 1);
        float xv8 = __shfl(A0[i], 2);
        float s = bl[lane] + xv0 * wr[0] + xv1 * wr[1] + xv2 * wr[2]
                + xv3 * wr[3] + xv4 * wr[4] + xv5 * wr[5] + xv6 * wr[6]
                + xv7 * wr[7] + xv8 * wr[8];
        if (nb + i < N)
            h1[(size_t)n[i] * 64 + lane] = f2bf(fmaxf(s, 0.f));
    }
}

// ---- 64-dim gather, 4 perm-nodes per wave: 4 edge-grp x 16 dim-grp -------

template<bool BIAS_RELU>
__global__ __launch_bounds__(256) void gather64v_kernel(
    const unsigned short* __restrict__ feat, const int* __restrict__ rs,
    const int* __restrict__ eidx, const int* __restrict__ perm,
    const float* __restrict__ bias, unsigned short* __restrict__ out, int N)
{
    int wid = threadIdx.x >> 6;
    int lane = threadIdx.x & 63;
    int g  = lane >> 4;     // edge group 0..3
    int d4 = lane & 15;     // dims 4*d4 .. 4*d4+3
    int nb = blockIdx.x * 16 + wid * 4;
    if (nb >= N) return;

    int n[4], e0[4], dg[4];
    float A0[4], A1[4], A2[4], A3[4];
    #pragma unroll
    for (int i = 0; i < 4; ++i) {
        n[i] = perm[min(nb + i, N - 1)];
        e0[i] = rs[n[i]];
        dg[i] = rs[n[i] + 1] - e0[i];
        A0[i] = A1[i] = A2[i] = A3[i] = 0.f;
    }
    #pragma unroll
    for (int i = 0; i < 4; ++i) {
        if (g == 0) {       // self term
            uint2 u = *(const uint2*)&feat[(size_t)n[i] * 64 + d4 * 4];
            A0[i] += lo16(u.x); A1[i] += hi16(u.x);
            A2[i] += lo16(u.y); A3[i] += hi16(u.y);
        }
    }
    int mdeg = max(max(dg[0], dg[1]), max(dg[2], dg[3]));
    for (int w0 = 0; w0 < mdeg; w0 += 64) {
        int sidx[4], wd[4];
        #pragma unroll
        for (int i = 0; i < 4; ++i) {
            wd[i] = min(max(dg[i] - w0, 0), 64);
            sidx[i] = (lane < wd[i]) ? eidx[e0[i] + w0 + lane] : 0;
        }
        int mwd = max(max(wd[0], wd[1]), max(wd[2], wd[3]));
        for (int c = 0; c < mwd; c += 8) {
            #pragma unroll
            for (int i = 0; i < 4; ++i) {
                int i0 = c + g, i1 = c + 4 + g;
                int s0 = __shfl(sidx[i], i0 < wd[i] ? i0 : 0);  // uniform flow
                int s1 = __shfl(sidx[i], i1 < wd[i] ? i1 : 0);
                float m0 = (i0 < wd[i]) ? 1.f : 0.f;
                float m1 = (i1 < wd[i]) ? 1.f : 0.f;
                uint2 u0 = *(const uint2*)&feat[(size_t)s0 * 64 + d4 * 4];
                uint2 u1 = *(const uint2*)&feat[(size_t)s1 * 64 + d4 * 4];
                A0[i] += m0 * lo16(u0.x) + m1 * lo16(u1.x);
                A1[i] += m0 * hi16(u0.x) + m1 * hi16(u1.x);
                A2[i] += m0 * lo16(u0.y) + m1 * lo16(u1.y);
                A3[i] += m0 * hi16(u0.y) + m1 * hi16(u1.y);
            }
        }
    }
    #pragma unroll
    for (int m = 16; m < 64; m <<= 1) {
        #pragma unroll
        for (int i = 0; i < 4; ++i) {
            A0[i] += __shfl_xor(A0[i], m); A1[i] += __shfl_xor(A1[i], m);
            A2[i] += __shfl_xor(A2[i], m); A3[i] += __shfl_xor(A3[i], m);
        }
    }
    float4 bv = make_float4(0.f, 0.f, 0.f, 0.f);
    if (BIAS_RELU) bv = *(const float4*)&bias[d4 * 4];
    #pragma unroll
    for (int i = 0; i < 4; ++i) {
        if (g == 0 && nb + i < N) {
            float a0 = A0[i], a1 = A1[i], a2 = A2[i], a3 = A3[i];
            if (BIAS_RELU) {
                a0 = fmaxf(a0 + bv.x, 0.f); a1 = fmaxf(a1 + bv.y, 0.f);
                a2 = fmaxf(a2 + bv.z, 0.f); a3 = fmaxf(a3 + bv.w, 0.f);
            }
            ushort4 u;
            u.x = f2bf(a0); u.y = f2bf(a1); u.z = f2bf(a2); u.w = f2bf(a3);
            *(ushort4*)&out[(size_t)n[i] * 64 + d4 * 4] = u;
        }
    }
}

// ---- MFMA linear: Y[n,:OUT] = relu?(A[n,:IN] @ W^T + bias), bf16 tables ---

template<int IN, int OUT, bool RELU>
__global__ __launch_bounds__(256) void linear_mfma_kernel(
    const unsigned short* __restrict__ A, const float* __restrict__ W,
    const float* __restrict__ bias, unsigned short* __restrict__ Y, int N)
{
    using s8v = __attribute__((ext_vector_type(8))) short;
    using f4v = __attribute__((ext_vector_type(4))) float;
    constexpr int KT = IN / 32;       // K-steps
    constexpr int CT = OUT / 16;      // col tiles
    constexpr int INP = IN + 8;       // padded row stride (ushorts)
    __shared__ __align__(16) unsigned short Wb[OUT * INP];
    __shared__ float bl[OUT];
    int tid = threadIdx.x;
    for (int i = tid; i < OUT * IN; i += 256) {
        int o = i / IN, k = i % IN;
        Wb[o * INP + k] = f2bf(W[i]);
    }
    for (int i = tid; i < OUT; i += 256) bl[i] = bias ? bias[i] : 0.f;
    __syncthreads();

    int w = tid >> 6, lane = tid & 63;
    int n0 = blockIdx.x * 64 + w * 16;
    int hl = lane >> 4;               // k-slice 0..3
    int ll = lane & 15;               // row (A) / col (B)

    int an = n0 + ll;
    if (an >= N) an = N - 1;          // clamp: garbage rows never written
    const unsigned short* arow = &A[(size_t)an * IN + hl * 8];
    s8v a[KT];
    #pragma unroll
    for (int ks = 0; ks < KT; ++ks) a[ks] = *(const s8v*)&arow[ks * 32];

    f4v acc[CT];
    #pragma unroll
    for (int c = 0; c < CT; ++c) acc[c] = (f4v){0.f, 0.f, 0.f, 0.f};
    #pragma unroll
    for (int c = 0; c < CT; ++c) {
        const unsigned short* wrow = &Wb[(c * 16 + ll) * INP + hl * 8];
        #pragma unroll
        for (int ks = 0; ks < KT; ++ks) {
            s8v b = *(const s8v*)&wrow[ks * 32];
            acc[c] = __builtin_amdgcn_mfma_f32_16x16x32_bf16(a[ks], b, acc[c], 0, 0, 0);
        }
    }
    #pragma unroll
    for (int c = 0; c < CT; ++c) {
        int col = c * 16 + ll;
        float bv = bl[col];
        #pragma unroll
        for (int r = 0; r < 4; ++r) {
            int gn = n0 + hl * 4 + r;
            if (gn < N) {
                float v = acc[c][r] + bv;
                if (RELU) v = fmaxf(v, 0.f);
                Y[(size_t)gn * OUT + col] = f2bf(v);
            }
        }
    }
}

// ---- pool + FC ------------------------------------------------------------

__device__ inline int lower_bound_i(const int* a, int n, int v) {
    int lo = 0, hi = n;
    while (lo < hi) {
        int mid = (lo + hi) >> 1;
        if (a[mid] < v) lo = mid + 1; else hi = mid;
    }
    return lo;
}

__global__ __launch_bounds__(256) void pool_fc_kernel(
    const unsigned short* __restrict__ h3, const int* __restrict__ batch,
    const float* __restrict__ Wfc, const float* __restrict__ bfc,
    float* __restrict__ out, int N)
{
    int g = blockIdx.x;
    int tid = threadIdx.x;
    int w = tid >> 6, lane = tid & 63;
    int lo = lower_bound_i(batch, N, g);
    int hi = lower_bound_i(batch, N, g + 1);
    float sum = 0.f;
    for (int i = lo + w; i < hi; i += 4)
        sum += bf2f(h3[(size_t)i * 64 + lane]);
    __shared__ float P[4][64];
    P[w][lane] = sum;
    __syncthreads();
    if (w == 0) {
        float s = P[0][lane] + P[1][lane] + P[2][lane] + P[3][lane];
        float cnt = (float)((hi - lo) > 0 ? (hi - lo) : 1);
        P[0][lane] = s / cnt;
    }
    __syncthreads();
    if (tid < 11) {
        float s = bfc[tid];
        const float* wr = &Wfc[tid * 64];
        #pragma unroll 8
        for (int k = 0; k < 64; ++k) s += P[0][k] * wr[k];
        out[g * 11 + tid] = s;
    }
}

// ---------------------------------------------------------------------------

extern "C" void kernel_launch(void* const* d_in, const int* in_sizes, int n_in,
                              void* d_out, int out_size, void* d_ws, size_t ws_size,
                              hipStream_t stream) {
    const float* x    = (const float*)d_in[0];
    const int*   ei   = (const int*)d_in[1];
    const int*   batch= (const int*)d_in[2];
    const float* W1   = (const float*)d_in[3];
    const float* b1   = (const float*)d_in[4];
    const float* W2   = (const float*)d_in[5];
    const float* b2   = (const float*)d_in[6];
    const float* W3   = (const float*)d_in[7];
    const float* b3   = (const float*)d_in[8];
    const float* Wfc  = (const float*)d_in[9];
    const float* bfc  = (const float*)d_in[10];
    float* out = (float*)d_out;

    const int N = in_sizes[2];
    const int E = in_sizes[1] / 2;
    const int G = out_size / 11;
    const int* src = ei;
    const int* dst = ei + E;
    const int NB = (N + RB - 1) / RB;      // buckets
    const int NT = NB * NBLK;              // edge count entries
    const int SB = (NT + SCBS - 1) / SCBS; // edge scan chunks
    const int NT2 = 256 * DBLK;            // degree count entries
    const int SB2 = (NT2 + SCBS - 1) / SCBS;

    // workspace (all bf16 tables):
    //   B1 64N (h1 -> t3) | B2 64N (buf2 -> h3) | B3 128N (h2) | XB 16N (xb)
    //   ints: pairs E | eidx E | rowstart N+1 | perm N |
    //         cnt NT | ofs NT | dcnt NT2 | dofs NT2 | part SCBS
    unsigned short* B1 = (unsigned short*)d_ws;
    unsigned short* B2 = B1 + (size_t)64 * N;
    unsigned short* B3 = B2 + (size_t)64 * N;
    unsigned short* XB = B3 + (size_t)128 * N;
    int* pairs    = (int*)(XB + (size_t)16 * N);
    int* eidx     = pairs + E;
    int* rowstart = eidx + E;
    int* perm     = rowstart + (N + 1);
    int* cnt      = perm + N;
    int* ofs      = cnt + NT;
    int* dcnt     = ofs + NT;
    int* dofs     = dcnt + NT2;
    int* part     = dofs + NT2;

    unsigned short* h1   = B1;
    unsigned short* buf2 = B2;
    unsigned short* h2   = B3;
    unsigned short* t3   = B1;   // h1 dead after gather2
    unsigned short* h3   = B2;   // buf2 dead after lin2
    unsigned short* xb   = XB;

    // ---- build: bucket-grouped pairs, per-bucket CSR ----
    count_kernel<<<NBLK, CFBS, 0, stream>>>(dst, cnt, E, NB);
    scan_k1<<<SB, SCBS, 0, stream>>>(cnt, ofs, part, NT);
    scan_k2<<<1, SCBS, 0, stream>>>(part, SB);
    scan_k3<<<SB, SCBS, 0, stream>>>(ofs, part, NT);
    fillp_kernel<<<NBLK, CFBS, 0, stream>>>(src, dst, ofs, pairs, E, NB);
    bucket_csr_kernel<<<NB, 512, 0, stream>>>(pairs, ofs, rowstart, eidx, N, E, NB);

    // ---- degree-sort perm (two-phase LDS-cursor counting sort) ----
    dcount_kernel<<<DBLK, 256, 0, stream>>>(rowstart, dcnt, N);
    scan_k1<<<SB2, SCBS, 0, stream>>>(dcnt, dofs, part, NT2);
    scan_k2<<<1, SCBS, 0, stream>>>(part, SB2);
    scan_k3<<<SB2, SCBS, 0, stream>>>(dofs, part, NT2);
    dfillk_kernel<<<DBLK, 256, 0, stream>>>(rowstart, dofs, perm, N);

    xprep_kernel<<<(N + 255) / 256, 256, 0, stream>>>(x, xb, N);

    // ---- layer 1: vectorized 9-dim gather + Lin 9->64 + relu ----
    node1v_kernel<<<(N + 15) / 16, 256, 0, stream>>>(
        xb, rowstart, eidx, perm, W1, b1, h1, N);

    // ---- layer 2 ----
    gather64v_kernel<false><<<(N + 15) / 16, 256, 0, stream>>>(
        h1, rowstart, eidx, perm, nullptr, buf2, N);
    linear_mfma_kernel<64, 128, true><<<(N + 63) / 64, 256, 0, stream>>>(
        buf2, W2, b2, h2, N);

    // ---- layer 3 ----
    linear_mfma_kernel<128, 64, false><<<(N + 63) / 64, 256, 0, stream>>>(
        h2, W3, nullptr, t3, N);
    gather64v_kernel<true><<<(N + 15) / 16, 256, 0, stream>>>(
        t3, rowstart, eidx, perm, b3, h3, N);

    // ---- pool + FC ----
    pool_fc_kernel<<<G, 256, 0, stream>>>(h3, batch, Wfc, bfc, out, N);
}

// Round 12
// 223.173 us; speedup vs baseline: 3.4152x; 1.0059x over previous
//
#include <hip/hip_runtime.h>
#include <hip/hip_bf16.h>

// ---------------------------------------------------------------------------
// GIN (3 layers, eps=0) + global mean pool + FC.
//
// Lessons: r1 global f32 atomics = 64B write-through; r2 per-node CSR fill =
//   105MB dirty lines; r3 block-per-bucket agg = latency collapse; r5 linears
//   LDS-read-bound -> r6 MFMA linears; r7 __shfl in divergent flow = garbage;
//   r8 1 node/wave = serial-chain bound; r9 4 nodes/wave interleaved (+ILP);
//   r10 per-node global atomics on 256 hot bins = RMW serialization; r11
//   degree-balanced waves = ZERO gather gain (padding theory falsified: the
//   gather sits at random-row L2-miss throughput ~2.4TB/s) -> sort dropped.
// r12: (a) natural order restored; (b) linear2+linear3 fused through an LDS
//   h2 tile (kills 51MB h2 round-trip); (c) gather inner loop 16 edges/iter
//   -> 16 row loads in flight per wave.
// ---------------------------------------------------------------------------

#define NBLK 256      // blocks for edge count/fill
#define CFBS 512      // threads for edge count/fill
#define RB   128      // nodes per bucket
#define NBMAX 1024    // max buckets (N <= 131072)
#define SCBS 1024     // scan chunk

__device__ inline float bf2f(unsigned short u) {
    return __uint_as_float((unsigned)u << 16);
}
__device__ inline unsigned short f2bf(float f) {
    unsigned x = __float_as_uint(f);
    return (unsigned short)((x + 0x7FFFu + ((x >> 16) & 1u)) >> 16);  // RNE
}
__device__ inline float lo16(unsigned u) { return __uint_as_float(u << 16); }
__device__ inline float hi16(unsigned u) { return __uint_as_float(u & 0xFFFF0000u); }

// ---- bucket build ---------------------------------------------------------

__global__ __launch_bounds__(CFBS) void count_kernel(
    const int* __restrict__ dst, int* __restrict__ cnt, int E, int NB)
{
    __shared__ int hist[NBMAX];
    int tid = threadIdx.x;
    for (int i = tid; i < NBMAX; i += CFBS) hist[i] = 0;
    __syncthreads();
    for (int e = blockIdx.x * CFBS + tid; e < E; e += NBLK * CFBS)
        atomicAdd(&hist[dst[e] >> 7], 1);
    __syncthreads();
    for (int b = tid; b < NB; b += CFBS)
        cnt[b * NBLK + blockIdx.x] = hist[b];
}

__global__ __launch_bounds__(SCBS) void scan_k1(
    const int* __restrict__ cnt, int* __restrict__ ofs,
    int* __restrict__ part, int NT)
{
    __shared__ int tmp[SCBS];
    int i = blockIdx.x * SCBS + threadIdx.x;
    int v = (i < NT) ? cnt[i] : 0;
    tmp[threadIdx.x] = v;
    __syncthreads();
    for (int off = 1; off < SCBS; off <<= 1) {
        int t = (threadIdx.x >= off) ? tmp[threadIdx.x - off] : 0;
        __syncthreads();
        tmp[threadIdx.x] += t;
        __syncthreads();
    }
    if (i < NT) ofs[i] = tmp[threadIdx.x] - v;   // exclusive within chunk
    if (threadIdx.x == SCBS - 1) part[blockIdx.x] = tmp[threadIdx.x];
}

__global__ __launch_bounds__(SCBS) void scan_k2(int* __restrict__ part, int B)
{
    __shared__ int tmp[SCBS];
    int v = (threadIdx.x < B) ? part[threadIdx.x] : 0;
    tmp[threadIdx.x] = v;
    __syncthreads();
    for (int off = 1; off < SCBS; off <<= 1) {
        int t = (threadIdx.x >= off) ? tmp[threadIdx.x - off] : 0;
        __syncthreads();
        tmp[threadIdx.x] += t;
        __syncthreads();
    }
    if (threadIdx.x < B) part[threadIdx.x] = tmp[threadIdx.x] - v;
}

__global__ __launch_bounds__(SCBS) void scan_k3(
    int* __restrict__ ofs, const int* __restrict__ part, int NT)
{
    int i = blockIdx.x * SCBS + threadIdx.x;
    if (i < NT) ofs[i] += part[blockIdx.x];
}

__global__ __launch_bounds__(CFBS) void fillp_kernel(
    const int* __restrict__ src, const int* __restrict__ dst,
    const int* __restrict__ ofs, int* __restrict__ pairs, int E, int NB)
{
    __shared__ int cur[NBMAX];
    int tid = threadIdx.x;
    for (int b = tid; b < NB; b += CFBS)
        cur[b] = ofs[b * NBLK + blockIdx.x];
    __syncthreads();
    for (int e = blockIdx.x * CFBS + tid; e < E; e += NBLK * CFBS) {
        int d = dst[e];
        int b = d >> 7, dl = d & 127;
        int pos = atomicAdd(&cur[b], 1);
        pairs[pos] = (dl << 20) | src[e];
    }
}

// per-bucket CSR finalize: writes land in bucket-local contiguous windows
__global__ __launch_bounds__(512) void bucket_csr_kernel(
    const int* __restrict__ pairs, const int* __restrict__ ofs,
    int* __restrict__ rowstart, int* __restrict__ eidx, int N, int E, int NB)
{
    __shared__ int deg[RB], pfx[RB], cur[RB];
    int tid = threadIdx.x;
    int b = blockIdx.x, n0 = b << 7;
    int e0 = ofs[b * NBLK];
    int e1 = (b + 1 < NB) ? ofs[(b + 1) * NBLK] : E;
    if (tid < RB) deg[tid] = 0;
    __syncthreads();
    for (int e = e0 + tid; e < e1; e += 512)
        atomicAdd(&deg[pairs[e] >> 20], 1);
    __syncthreads();
    if (tid < RB) pfx[tid] = deg[tid];
    __syncthreads();
    for (int off = 1; off < RB; off <<= 1) {
        int t = (tid < RB && tid >= off) ? pfx[tid - off] : 0;
        __syncthreads();
        if (tid < RB) pfx[tid] += t;
        __syncthreads();
    }
    if (tid < RB) {
        int ex = pfx[tid] - deg[tid];     // exclusive
        cur[tid] = ex;
        int n = n0 + tid;
        if (n < N) rowstart[n] = e0 + ex;
    }
    if (b == NB - 1 && tid == 0) rowstart[N] = E;
    __syncthreads();
    for (int e = e0 + tid; e < e1; e += 512) {
        int p = pairs[e];
        int pos = e0 + atomicAdd(&cur[p >> 20], 1);
        eidx[pos] = p & 0xFFFFF;
    }
}

// ---- x prep: xb[N][16] bf16 (pad 9->16) ----------------------------------

__global__ __launch_bounds__(256) void xprep_kernel(
    const float* __restrict__ x, unsigned short* __restrict__ xb, int N)
{
    int n = blockIdx.x * 256 + threadIdx.x;
    if (n >= N) return;
    unsigned short r[16];
    #pragma unroll
    for (int k = 0; k < 9; ++k) r[k] = f2bf(x[(size_t)n * 9 + k]);
    #pragma unroll
    for (int k = 9; k < 16; ++k) r[k] = 0;
    uint4 u0, u1;
    u0.x = r[0] | ((unsigned)r[1] << 16);  u0.y = r[2] | ((unsigned)r[3] << 16);
    u0.z = r[4] | ((unsigned)r[5] << 16);  u0.w = r[6] | ((unsigned)r[7] << 16);
    u1.x = r[8] | ((unsigned)r[9] << 16);  u1.y = 0; u1.z = 0; u1.w = 0;
    *(uint4*)&xb[(size_t)n * 16]     = u0;
    *(uint4*)&xb[(size_t)n * 16 + 8] = u1;
}

// ---- layer 1: 9-dim gather + Lin 9->64 + relu, 4 nodes per wave ----------

__global__ __launch_bounds__(256) void node1v_kernel(
    const unsigned short* __restrict__ xb, const int* __restrict__ rs,
    const int* __restrict__ eidx, const float* __restrict__ W1,
    const float* __restrict__ b1, unsigned short* __restrict__ h1, int N)
{
    __shared__ float Wl[576];
    __shared__ float bl[64];
    for (int i = threadIdx.x; i < 576; i += 256) Wl[i] = W1[i];
    if (threadIdx.x < 64) bl[threadIdx.x] = b1[threadIdx.x];
    __syncthreads();
    int wid = threadIdx.x >> 6;
    int lane = threadIdx.x & 63;
    int g  = lane >> 2;     // edge group 0..15
    int d4 = lane & 3;      // dims 4*d4 .. 4*d4+3
    int nb = blockIdx.x * 16 + wid * 4;   // this wave's 4 nodes
    if (nb >= N) return;

    int n[4], e0[4], dg[4];
    float A0[4], A1[4], A2[4], A3[4];
    #pragma unroll
    for (int i = 0; i < 4; ++i) {
        n[i] = min(nb + i, N - 1);
        e0[i] = rs[n[i]];
        dg[i] = rs[n[i] + 1] - e0[i];
        A0[i] = A1[i] = A2[i] = A3[i] = 0.f;
    }
    #pragma unroll
    for (int i = 0; i < 4; ++i) {
        if (g == 0) {       // self term
            uint2 u = *(const uint2*)&xb[(size_t)n[i] * 16 + d4 * 4];
            A0[i] += lo16(u.x); A1[i] += hi16(u.x);
            A2[i] += lo16(u.y); A3[i] += hi16(u.y);
        }
    }
    int mdeg = max(max(dg[0], dg[1]), max(dg[2], dg[3]));
    for (int w0 = 0; w0 < mdeg; w0 += 64) {
        int sidx[4], wd[4];
        #pragma unroll
        for (int i = 0; i < 4; ++i) {
            wd[i] = min(max(dg[i] - w0, 0), 64);
            sidx[i] = (lane < wd[i]) ? eidx[e0[i] + w0 + lane] : 0;
        }
        int mwd = max(max(wd[0], wd[1]), max(wd[2], wd[3]));
        for (int c = 0; c < mwd; c += 16) {
            #pragma unroll
            for (int i = 0; i < 4; ++i) {
                int idx = c + g;
                int s = __shfl(sidx[i], idx < wd[i] ? idx : 0); // uniform flow
                float m = (idx < wd[i]) ? 1.f : 0.f;
                uint2 u = *(const uint2*)&xb[(size_t)s * 16 + d4 * 4];
                A0[i] += m * lo16(u.x); A1[i] += m * hi16(u.x);
                A2[i] += m * lo16(u.y); A3[i] += m * hi16(u.y);
            }
        }
    }
    #pragma unroll
    for (int m = 4; m < 64; m <<= 1) {
        #pragma unroll
        for (int i = 0; i < 4; ++i) {
            A0[i] += __shfl_xor(A0[i], m); A1[i] += __shfl_xor(A1[i], m);
            A2[i] += __shfl_xor(A2[i], m); A3[i] += __shfl_xor(A3[i], m);
        }
    }
    const float* wr = &Wl[lane * 9];
    #pragma unroll
    for (int i = 0; i < 4; ++i) {
        float xv0 = __shfl(A0[i], 0), xv1 = __shfl(A1[i], 0);
        float xv2 = __shfl(A2[i], 0), xv3 = __shfl(A3[i], 0);
        float xv4 = __shfl(A0[i], 1), xv5 = __shfl(A1[i], 1);
        float xv6 = __shfl(A2[i], 1), xv7 = __shfl(A3[i], 1);
        float xv8 = __shfl(A0[i], 2);
        float s = bl[lane] + xv0 * wr[0] + xv1 * wr[1] + xv2 * wr[2]
                + xv3 * wr[3] + xv4 * wr[4] + xv5 * wr[5] + xv6 * wr[6]
                + xv7 * wr[7] + xv8 * wr[8];
        if (nb + i < N)
            h1[(size_t)(nb + i) * 64 + lane] = f2bf(fmaxf(s, 0.f));
    }
}

// ---- 64-dim gather, 4 nodes/wave, 16 edges per inner iter (16 loads deep)

template<bool BIAS_RELU>
__global__ __launch_bounds__(256) void gather64v_kernel(
    const unsigned short* __restrict__ feat, const int* __restrict__ rs,
    const int* __restrict__ eidx, const float* __restrict__ bias,
    unsigned short* __restrict__ out, int N)
{
    int wid = threadIdx.x >> 6;
    int lane = threadIdx.x & 63;
    int g  = lane >> 4;     // edge group 0..3
    int d4 = lane & 15;     // dims 4*d4 .. 4*d4+3
    int nb = blockIdx.x * 16 + wid * 4;
    if (nb >= N) return;

    int n[4], e0[4], dg[4];
    float A0[4], A1[4], A2[4], A3[4];
    #pragma unroll
    for (int i = 0; i < 4; ++i) {
        n[i] = min(nb + i, N - 1);
        e0[i] = rs[n[i]];
        dg[i] = rs[n[i] + 1] - e0[i];
        A0[i] = A1[i] = A2[i] = A3[i] = 0.f;
    }
    #pragma unroll
    for (int i = 0; i < 4; ++i) {
        if (g == 0) {       // self term
            uint2 u = *(const uint2*)&feat[(size_t)n[i] * 64 + d4 * 4];
            A0[i] += lo16(u.x); A1[i] += hi16(u.x);
            A2[i] += lo16(u.y); A3[i] += hi16(u.y);
        }
    }
    int mdeg = max(max(dg[0], dg[1]), max(dg[2], dg[3]));
    for (int w0 = 0; w0 < mdeg; w0 += 64) {
        int sidx[4], wd[4];
        #pragma unroll
        for (int i = 0; i < 4; ++i) {
            wd[i] = min(max(dg[i] - w0, 0), 64);
            sidx[i] = (lane < wd[i]) ? eidx[e0[i] + w0 + lane] : 0;
        }
        int mwd = max(max(wd[0], wd[1]), max(wd[2], wd[3]));
        for (int c = 0; c < mwd; c += 16) {
            #pragma unroll
            for (int i = 0; i < 4; ++i) {   // 16 independent loads in flight
                int i0 = c + g, i1 = c + 4 + g;
                int i2 = c + 8 + g, i3 = c + 12 + g;
                int s0 = __shfl(sidx[i], i0 < wd[i] ? i0 : 0);  // uniform flow
                int s1 = __shfl(sidx[i], i1 < wd[i] ? i1 : 0);
                int s2 = __shfl(sidx[i], i2 < wd[i] ? i2 : 0);
                int s3 = __shfl(sidx[i], i3 < wd[i] ? i3 : 0);
                float m0 = (i0 < wd[i]) ? 1.f : 0.f;
                float m1 = (i1 < wd[i]) ? 1.f : 0.f;
                float m2 = (i2 < wd[i]) ? 1.f : 0.f;
                float m3 = (i3 < wd[i]) ? 1.f : 0.f;
                uint2 u0 = *(const uint2*)&feat[(size_t)s0 * 64 + d4 * 4];
                uint2 u1 = *(const uint2*)&feat[(size_t)s1 * 64 + d4 * 4];
                uint2 u2 = *(const uint2*)&feat[(size_t)s2 * 64 + d4 * 4];
                uint2 u3 = *(const uint2*)&feat[(size_t)s3 * 64 + d4 * 4];
                A0[i] += (m0 * lo16(u0.x) + m1 * lo16(u1.x))
                       + (m2 * lo16(u2.x) + m3 * lo16(u3.x));
                A1[i] += (m0 * hi16(u0.x) + m1 * hi16(u1.x))
                       + (m2 * hi16(u2.x) + m3 * hi16(u3.x));
                A2[i] += (m0 * lo16(u0.y) + m1 * lo16(u1.y))
                       + (m2 * lo16(u2.y) + m3 * lo16(u3.y));
                A3[i] += (m0 * hi16(u0.y) + m1 * hi16(u1.y))
                       + (m2 * hi16(u2.y) + m3 * hi16(u3.y));
            }
        }
    }
    #pragma unroll
    for (int m = 16; m < 64; m <<= 1) {
        #pragma unroll
        for (int i = 0; i < 4; ++i) {
            A0[i] += __shfl_xor(A0[i], m); A1[i] += __shfl_xor(A1[i], m);
            A2[i] += __shfl_xor(A2[i], m); A3[i] += __shfl_xor(A3[i], m);
        }
    }
    float4 bv = make_float4(0.f, 0.f, 0.f, 0.f);
    if (BIAS_RELU) bv = *(const float4*)&bias[d4 * 4];
    #pragma unroll
    for (int i = 0; i < 4; ++i) {
        if (g == 0 && nb + i < N) {
            float a0 = A0[i], a1 = A1[i], a2 = A2[i], a3 = A3[i];
            if (BIAS_RELU) {
                a0 = fmaxf(a0 + bv.x, 0.f); a1 = fmaxf(a1 + bv.y, 0.f);
                a2 = fmaxf(a2 + bv.z, 0.f); a3 = fmaxf(a3 + bv.w, 0.f);
            }
            ushort4 u;
            u.x = f2bf(a0); u.y = f2bf(a1); u.z = f2bf(a2); u.w = f2bf(a3);
            *(ushort4*)&out[(size_t)(nb + i) * 64 + d4 * 4] = u;
        }
    }
}

// ---- fused linear2+linear3: t3 = W3 . relu(W2 . a + b2) -------------------
// Block: 64 nodes, 4 waves; wave = 16-node strip. h2 (64x128 bf16) lives in
// an LDS tile (wave-private strips -> no barrier in the main path). Layouts:
//   A-frag 16x16x32: lane l -> row l&15, k-slice (l>>4)*8
//   C/D:             col = lane&15, row = (lane>>4)*4 + reg  [m89-verified]
// Padded strides (+8 ushorts) -> 2-way bank alias only (free, m136).

__global__ __launch_bounds__(256) void linear23_fused_kernel(
    const unsigned short* __restrict__ A, const float* __restrict__ W2,
    const float* __restrict__ b2, const float* __restrict__ W3,
    unsigned short* __restrict__ t3, int N)
{
    using s8v = __attribute__((ext_vector_type(8))) short;
    using f4v = __attribute__((ext_vector_type(4))) float;
    __shared__ __align__(16) unsigned short Wb2[128 * 72];   // W2[o][k], o<128,k<64
    __shared__ __align__(16) unsigned short Wb3[64 * 136];   // W3[o][k], o<64,k<128
    __shared__ __align__(16) unsigned short H2[64 * 136];    // h2 tile [node][128]
    __shared__ float bl2[128];
    int tid = threadIdx.x;
    for (int i = tid; i < 128 * 64; i += 256) {
        int o = i >> 6, k = i & 63;
        Wb2[o * 72 + k] = f2bf(W2[i]);
    }
    for (int i = tid; i < 64 * 128; i += 256) {
        int o = i >> 7, k = i & 127;
        Wb3[o * 136 + k] = f2bf(W3[i]);
    }
    if (tid < 128) bl2[tid] = b2[tid];
    __syncthreads();

    int w = tid >> 6, lane = tid & 63;
    int n0 = blockIdx.x * 64 + w * 16;
    int hl = lane >> 4;               // k-slice 0..3
    int ll = lane & 15;               // row (A) / col (B)

    // ---- stage 1: h2 = relu(A @ W2^T + b2) -> LDS strip ----
    int an = min(n0 + ll, N - 1);     // clamp: junk rows stay in LDS only
    const unsigned short* arow = &A[(size_t)an * 64 + hl * 8];
    s8v a1[2];
    a1[0] = *(const s8v*)&arow[0];
    a1[1] = *(const s8v*)&arow[32];

    #pragma unroll
    for (int c = 0; c < 8; ++c) {
        f4v acc = (f4v){0.f, 0.f, 0.f, 0.f};
        const unsigned short* wrow = &Wb2[(c * 16 + ll) * 72 + hl * 8];
        acc = __builtin_amdgcn_mfma_f32_16x16x32_bf16(a1[0], *(const s8v*)&wrow[0],  acc, 0, 0, 0);
        acc = __builtin_amdgcn_mfma_f32_16x16x32_bf16(a1[1], *(const s8v*)&wrow[32], acc, 0, 0, 0);
        int col = c * 16 + ll;
        float bv = bl2[col];
        #pragma unroll
        for (int r = 0; r < 4; ++r) {
            int nrow = w * 16 + hl * 4 + r;          // block-local node row
            H2[nrow * 136 + col] = f2bf(fmaxf(acc[r] + bv, 0.f));
        }
    }
    // wave-private strip: same wave wrote rows w*16..w*16+15 it now reads;
    // compiler inserts lgkmcnt waits. No cross-wave sharing -> no barrier.

    // ---- stage 2: t3 = h2 @ W3^T ----
    const unsigned short* hrow = &H2[(w * 16 + ll) * 136 + hl * 8];
    s8v a2[4];
    #pragma unroll
    for (int ks = 0; ks < 4; ++ks) a2[ks] = *(const s8v*)&hrow[ks * 32];

    #pragma unroll
    for (int c = 0; c < 4; ++c) {
        f4v acc = (f4v){0.f, 0.f, 0.f, 0.f};
        const unsigned short* wrow = &Wb3[(c * 16 + ll) * 136 + hl * 8];
        #pragma unroll
        for (int ks = 0; ks < 4; ++ks)
            acc = __builtin_amdgcn_mfma_f32_16x16x32_bf16(a2[ks], *(const s8v*)&wrow[ks * 32], acc, 0, 0, 0);
        int col = c * 16 + ll;
        #pragma unroll
        for (int r = 0; r < 4; ++r) {
            int gn = n0 + hl * 4 + r;
            if (gn < N)
                t3[(size_t)gn * 64 + col] = f2bf(acc[r]);
        }
    }
}

// ---- pool + FC ------------------------------------------------------------

__device__ inline int lower_bound_i(const int* a, int n, int v) {
    int lo = 0, hi = n;
    while (lo < hi) {
        int mid = (lo + hi) >> 1;
        if (a[mid] < v) lo = mid + 1; else hi = mid;
    }
    return lo;
}

__global__ __launch_bounds__(256) void pool_fc_kernel(
    const unsigned short* __restrict__ h3, const int* __restrict__ batch,
    const float* __restrict__ Wfc, const float* __restrict__ bfc,
    float* __restrict__ out, int N)
{
    int g = blockIdx.x;
    int tid = threadIdx.x;
    int w = tid >> 6, lane = tid & 63;
    int lo = lower_bound_i(batch, N, g);
    int hi = lower_bound_i(batch, N, g + 1);
    float sum = 0.f;
    for (int i = lo + w; i < hi; i += 4)
        sum += bf2f(h3[(size_t)i * 64 + lane]);
    __shared__ float P[4][64];
    P[w][lane] = sum;
    __syncthreads();
    if (w == 0) {
        float s = P[0][lane] + P[1][lane] + P[2][lane] + P[3][lane];
        float cnt = (float)((hi - lo) > 0 ? (hi - lo) : 1);
        P[0][lane] = s / cnt;
    }
    __syncthreads();
    if (tid < 11) {
        float s = bfc[tid];
        const float* wr = &Wfc[tid * 64];
        #pragma unroll 8
        for (int k = 0; k < 64; ++k) s += P[0][k] * wr[k];
        out[g * 11 + tid] = s;
    }
}

// ---------------------------------------------------------------------------

extern "C" void kernel_launch(void* const* d_in, const int* in_sizes, int n_in,
                              void* d_out, int out_size, void* d_ws, size_t ws_size,
                              hipStream_t stream) {
    const float* x    = (const float*)d_in[0];
    const int*   ei   = (const int*)d_in[1];
    const int*   batch= (const int*)d_in[2];
    const float* W1   = (const float*)d_in[3];
    const float* b1   = (const float*)d_in[4];
    const float* W2   = (const float*)d_in[5];
    const float* b2   = (const float*)d_in[6];
    const float* W3   = (const float*)d_in[7];
    const float* b3   = (const float*)d_in[8];
    const float* Wfc  = (const float*)d_in[9];
    const float* bfc  = (const float*)d_in[10];
    float* out = (float*)d_out;

    const int N = in_sizes[2];
    const int E = in_sizes[1] / 2;
    const int G = out_size / 11;
    const int* src = ei;
    const int* dst = ei + E;
    const int NB = (N + RB - 1) / RB;      // buckets
    const int NT = NB * NBLK;              // count entries
    const int SB = (NT + SCBS - 1) / SCBS; // scan chunks

    // workspace (bf16 tables):
    //   B1 64N (h1 -> t3) | B2 64N (buf2 -> h3) | XB 16N (xb)
    //   ints: pairs E | eidx E | rowstart N+1 | cnt NT | ofs NT | part SCBS
    unsigned short* B1 = (unsigned short*)d_ws;
    unsigned short* B2 = B1 + (size_t)64 * N;
    unsigned short* XB = B2 + (size_t)64 * N;
    int* pairs    = (int*)(XB + (size_t)16 * N);
    int* eidx     = pairs + E;
    int* rowstart = eidx + E;
    int* cnt      = rowstart + (N + 1);
    int* ofs      = cnt + NT;
    int* part     = ofs + NT;

    unsigned short* h1   = B1;
    unsigned short* buf2 = B2;
    unsigned short* t3   = B1;   // h1 dead after gather2
    unsigned short* h3   = B2;   // buf2 dead after fused linear
    unsigned short* xb   = XB;

    // ---- build: bucket-grouped pairs, then per-bucket CSR ----
    count_kernel<<<NBLK, CFBS, 0, stream>>>(dst, cnt, E, NB);
    scan_k1<<<SB, SCBS, 0, stream>>>(cnt, ofs, part, NT);
    scan_k2<<<1, SCBS, 0, stream>>>(part, SB);
    scan_k3<<<SB, SCBS, 0, stream>>>(ofs, part, NT);
    fillp_kernel<<<NBLK, CFBS, 0, stream>>>(src, dst, ofs, pairs, E, NB);
    bucket_csr_kernel<<<NB, 512, 0, stream>>>(pairs, ofs, rowstart, eidx, N, E, NB);
    xprep_kernel<<<(N + 255) / 256, 256, 0, stream>>>(x, xb, N);

    // ---- layer 1: vectorized 9-dim gather + Lin 9->64 + relu ----
    node1v_kernel<<<(N + 15) / 16, 256, 0, stream>>>(
        xb, rowstart, eidx, W1, b1, h1, N);

    // ---- layer 2 gather, then fused Lin2+Lin3 (h2 never leaves LDS) ----
    gather64v_kernel<false><<<(N + 15) / 16, 256, 0, stream>>>(
        h1, rowstart, eidx, nullptr, buf2, N);
    linear23_fused_kernel<<<(N + 63) / 64, 256, 0, stream>>>(
        buf2, W2, b2, W3, t3, N);

    // ---- layer 3 gather (+b3, relu) ----
    gather64v_kernel<true><<<(N + 15) / 16, 256, 0, stream>>>(
        t3, rowstart, eidx, b3, h3, N);

    // ---- pool + FC ----
    pool_fc_kernel<<<G, 256, 0, stream>>>(h3, batch, Wfc, bfc, out, N);
}